// Round 6
// baseline (139.251 us; speedup 1.0000x reference)
//
#include <hip/hip_runtime.h>
#include <hip/hip_bf16.h>

typedef __bf16 bf16;
typedef __bf16 bf16x8 __attribute__((ext_vector_type(8)));
typedef float f32x16 __attribute__((ext_vector_type(16)));

__device__ __forceinline__ void gload_lds16(const void* g, void* l) {
  __builtin_amdgcn_global_load_lds(
      (const __attribute__((address_space(1))) void*)g,
      (__attribute__((address_space(3))) void*)l, 16, 0, 0);
}

// ---------------------------------------------------------------------------
// C = A[M,K] @ B[N,K]^T (row-major, K inner). bf16 in, f32 accum.
// EPI=0: f32 store. EPI=1: sigmoid -> bf16 store.
// 128x128 tile, BK=32, 256 thr = 4 waves (2x2), wave tile 64x64 as 2x2 frags
// of v_mfma_f32_32x32x16_bf16 (4096 FLOP/cyc vs 3380 for 16x16x32; half the
// MFMA instruction issues).  A/B frags read with IDENTICAL per-lane k-offsets
// -> any internal k-slot permutation cancels (applied to both operands).
// T3+T4: triple-buffered LDS (3 x 16KB), one raw s_barrier/iter, counted
// vmcnt(4); stage(t+2) issued after barrier -> loads get ~2 iters to land.
// T2 swizzle (r2/r4/r5-validated): linear gload_lds dest + source col16 ^=
// ((row>>1)&3)<<4 + same XOR on ds_read byte offset.
// ---------------------------------------------------------------------------
template <int EPI>
__global__ __launch_bounds__(256, 3) void gemm_bt(
    const bf16* __restrict__ A, const bf16* __restrict__ Bw,
    void* __restrict__ C, int M, int N, int K) {
  __shared__ __align__(16) char smem[49152];  // buf b at b*16K: A 8K, B 8K
  const int tid = threadIdx.x;
  const int lane = tid & 63;
  const int wave = tid >> 6;

  const int nb = N >> 7;
  const int nwg = gridDim.x;
  const int q8 = nwg >> 3;  // grids divisible by 8
  const int tile = ((int)blockIdx.x & 7) * q8 + ((int)blockIdx.x >> 3);
  const int m0 = (tile / nb) << 7;
  const int n0 = (tile % nb) << 7;

  const int wm = (wave >> 1) << 6;
  const int wn = (wave & 1) << 6;

  f32x16 acc[2][2] = {};

  // staging constants: thread covers 4 chunks (chunk = wave + 4c), 16 rows each
  const int r_in = lane >> 2;                        // row within 16-row chunk
  const int swz = ((lane >> 3) & 3) << 4;            // ((r_in>>1)&3)<<4
  const int scol = (((lane & 3) << 4) ^ swz) >> 1;   // source col (elements)
  const int ldst_lin = lane << 4;                    // linear dest within chunk

  auto stage = [&](int t, int buf) {
    const int k0 = t << 5;
#pragma unroll
    for (int c = 0; c < 4; ++c) {
      const int chunk = wave + (c << 2);  // wave-uniform 0..15
      char* ldst = smem + buf * 16384 + chunk * 1024 + ldst_lin;
      const bf16* gsrc;
      if (chunk < 8) {
        const int row = m0 + (chunk << 4) + r_in;
        gsrc = A + (size_t)row * K + k0 + scol;
      } else {
        const int row = n0 + ((chunk - 8) << 4) + r_in;
        gsrc = Bw + (size_t)row * K + k0 + scol;
      }
      gload_lds16(gsrc, ldst);
    }
  };

  // ds_read constants (32x32x16 frags): row = lane&31, k16 = (lane>>5)*16B,
  // byte col = (kk*32 + k16) ^ swzr, swzr = ((row>>1)&3)<<4 (bits 1-2 of row).
  const int row32 = lane & 31;
  const int kgrp = (lane >> 5) << 4;
  const int swzr = ((row32 >> 1) & 3) << 4;

  const int nt = K >> 5;  // 32 for K=1024

  stage(0, 0);
  stage(1, 1);

  int buf = 0;
  for (int t = 0; t < nt; ++t) {
    if (t == nt - 1) {
      asm volatile("s_waitcnt vmcnt(0)" ::: "memory");
    } else {
      asm volatile("s_waitcnt vmcnt(4)" ::: "memory");  // stage(t) landed
    }
    __builtin_amdgcn_s_barrier();
    __builtin_amdgcn_sched_barrier(0);

    bf16x8 af[2][2], bg[2][2];  // [kk][frag]
    const char* base = smem + buf * 16384;
#pragma unroll
    for (int kk = 0; kk < 2; ++kk) {
      const int kc = (kk << 5);
#pragma unroll
      for (int i = 0; i < 2; ++i) {
        af[kk][i] = *(const bf16x8*)(base + (wm + (i << 5) + row32) * 64 +
                                     ((kc + kgrp) ^ swzr));
        bg[kk][i] = *(const bf16x8*)(base + 8192 + (wn + (i << 5) + row32) * 64 +
                                     ((kc + kgrp) ^ swzr));
      }
    }

    if (t + 2 < nt) {
      int pb = buf + 2;
      if (pb >= 3) pb -= 3;
      stage(t + 2, pb);
    }

    asm volatile("s_waitcnt lgkmcnt(0)" ::: "memory");  // ds_reads complete
    __builtin_amdgcn_sched_barrier(0);                  // rule #18

#pragma unroll
    for (int kk = 0; kk < 2; ++kk)
#pragma unroll
      for (int i = 0; i < 2; ++i)
#pragma unroll
        for (int j = 0; j < 2; ++j)
          acc[i][j] = __builtin_amdgcn_mfma_f32_32x32x16_bf16(
              af[kk][i], bg[kk][j], acc[i][j], 0, 0, 0);

    if (++buf == 3) buf = 0;
  }

  // epilogue: C/D layout col=lane&31, row=(reg&3)+8*(reg>>2)+4*(lane>>5)
  const int col0 = n0 + wn + row32;
  const int rowb = m0 + wm + ((lane >> 5) << 2);
#pragma unroll
  for (int i = 0; i < 2; ++i)
#pragma unroll
    for (int j = 0; j < 2; ++j)
#pragma unroll
      for (int r = 0; r < 16; ++r) {
        const int rrow = rowb + (i << 5) + (r & 3) + ((r >> 2) << 3);
        const size_t idx = (size_t)rrow * N + (col0 + (j << 5));
        const float v = acc[i][j][r];
        if (EPI == 1) {
          ((bf16*)C)[idx] = (bf16)(1.0f / (1.0f + __expf(-v)));
        } else {
          ((float*)C)[idx] = v;
        }
      }
}

// ---------------------------------------------------------------------------
// Windowed Hamming attention + gate.  One thread per (b,s,h).
// ---------------------------------------------------------------------------
__global__ __launch_bounds__(256) void rosa_attn(
    const bf16* __restrict__ qkv, const float* __restrict__ emb0,
    const float* __restrict__ emb1, bf16* __restrict__ G) {
  const int t = blockIdx.x * 256 + threadIdx.x;
  const int row = t >> 7;
  const int h = t & 127;
  const int sp = row & 4095;

  const bf16* qptr = qkv + (size_t)row * 3072 + h * 8;
  bf16x8 qv = *(const bf16x8*)qptr;
  float qb[8], qsum = 0.f;
#pragma unroll
  for (int c = 0; c < 8; ++c) {
    qb[c] = (float)qv[c];
    qsum += qb[c];
  }

  float oacc[8] = {};
  float wsum = 0.f;
  const int wmax = (sp + 1 < 8) ? (sp + 1) : 8;
  const float scale = 0.35355339059327373f;

  for (int d = 0; d < wmax; ++d) {
    const bf16* base = qkv + (size_t)(row - d) * 3072 + h * 8;
    bf16x8 kv = *(const bf16x8*)(base + 1024);
    bf16x8 vv = *(const bf16x8*)(base + 2048);
    float dot = 0.f, ksum = 0.f;
#pragma unroll
    for (int c = 0; c < 8; ++c) {
      const float kb = (float)kv[c];
      dot += qb[c] * kb;
      ksum += kb;
    }
    const float score = (8.0f + 2.0f * dot - qsum - ksum) * scale;
    const float w = __expf(score);
    wsum += w;
#pragma unroll
    for (int c = 0; c < 8; ++c) oacc[c] += w * (float)vv[c];
  }

  const float inv = 1.0f / wsum;
  const int e0i = h * 8;
  bf16x8 outv;
#pragma unroll
  for (int c = 0; c < 8; ++c) {
    const float o = oacc[c] * inv;
    const float e0 = emb0[e0i + c], e1 = emb1[e0i + c];
    outv[c] = (bf16)(e0 + (e1 - e0) * o);
  }
  *(bf16x8*)(G + (size_t)row * 1024 + h * 8) = outv;
}

// ---------------------------------------------------------------------------
// One launch converts X, Wq, Wk, Wv, Wo -> bf16.  8 f32 per thread.
// blocks: [0,4096) X | [4096,4608) Wq | [4608,5120) Wk | [5120,5632) Wv |
// [5632,6144) Wo
// ---------------------------------------------------------------------------
__global__ __launch_bounds__(256) void cvt_all(
    const float* __restrict__ X, const float* __restrict__ Wq,
    const float* __restrict__ Wk, const float* __restrict__ Wv,
    const float* __restrict__ Wo, bf16* __restrict__ Xb,
    bf16* __restrict__ Wqkvb, bf16* __restrict__ Wob) {
  const int b = blockIdx.x;
  const float* src;
  bf16* dst;
  int off;
  if (b < 4096)      { src = X;  dst = Xb;            off = b; }
  else if (b < 4608) { src = Wq; dst = Wqkvb;          off = b - 4096; }
  else if (b < 5120) { src = Wk; dst = Wqkvb + 1048576; off = b - 4608; }
  else if (b < 5632) { src = Wv; dst = Wqkvb + 2097152; off = b - 5120; }
  else               { src = Wo; dst = Wob;            off = b - 5632; }
  const int i = (off * 256 + threadIdx.x) * 8;
  const float4 a = *(const float4*)(src + i);
  const float4 c = *(const float4*)(src + i + 4);
  bf16x8 o;
  o[0] = (bf16)a.x; o[1] = (bf16)a.y; o[2] = (bf16)a.z; o[3] = (bf16)a.w;
  o[4] = (bf16)c.x; o[5] = (bf16)c.y; o[6] = (bf16)c.z; o[7] = (bf16)c.w;
  *(bf16x8*)(dst + i) = o;
}

// ---------------------------------------------------------------------------
extern "C" void kernel_launch(void* const* d_in, const int* in_sizes, int n_in,
                              void* d_out, int out_size, void* d_ws,
                              size_t ws_size, hipStream_t stream) {
  const float* X = (const float*)d_in[0];
  const float* Wq = (const float*)d_in[1];
  const float* Wk = (const float*)d_in[2];
  const float* Wv = (const float*)d_in[3];
  const float* Wo = (const float*)d_in[4];
  const float* emb0 = (const float*)d_in[5];
  const float* emb1 = (const float*)d_in[6];

  char* ws = (char*)d_ws;
  bf16* Xb    = (bf16*)(ws + 0);          // 8192*1024   (16 MB)
  bf16* Wqkvb = (bf16*)(ws + 16777216);   // 3072*1024   (6 MB)
  bf16* Wob   = (bf16*)(ws + 23068672);   // 1024*1024   (2 MB)
  bf16* QKVb  = (bf16*)(ws + 25165824);   // 8192*3072   (48 MB)
  bf16* G     = (bf16*)(ws + 75497472);   // 8192*1024   (16 MB)
  float* out  = (float*)d_out;

  // all f32 -> bf16 conversions in one launch
  cvt_all<<<6144, 256, 0, stream>>>(X, Wq, Wk, Wv, Wo, Xb, Wqkvb, Wob);

  // fused QKV projection + sigmoid -> bf16 (M=8192, N=3072, K=1024)
  gemm_bt<1><<<64 * 24, 256, 0, stream>>>(Xb, Wqkvb, QKVb, 8192, 3072, 1024);

  // windowed attention + gate -> bf16
  rosa_attn<<<4096, 256, 0, stream>>>(QKVb, emb0, emb1, G);

  // output projection -> f32 (M=8192, N=1024, K=1024)
  gemm_bt<0><<<64 * 8, 256, 0, stream>>>(G, Wob, out, 8192, 1024, 1024);
}